// Round 1
// baseline (254.656 us; speedup 1.0000x reference)
//
#include <hip/hip_runtime.h>
#include <hip/hip_bf16.h>
#include <cstddef>
#include <cstdint>

#define BB 32
#define NN 4096
#define KK 8
#define DD 256
#define HH 512
#define LN_EPS 1e-5f
#define SCALE 0.0625f  // 1/sqrt(256)
#define NCHUNK 32      // attn partial chunks per batch (32 -> 1024 blocks = 4/CU, 16 waves/CU)

__device__ __forceinline__ float wave_sum(float v) {
#pragma unroll
  for (int off = 32; off >= 1; off >>= 1) v += __shfl_xor(v, off);
  return v;
}

__device__ __forceinline__ float sigmoidf_(float x) { return 1.0f / (1.0f + __expf(-x)); }

// packed bf16 weight pool offsets (elements).
// layout per matrix (OUT outputs, K inputs): elem(k,j) at (k>>2)*OUT*4 + j*4 + (k&3)
#define OFF_G   0        // 6 gate matrices [ih_r,ih_z,ih_n,hh_r,hh_z,hh_n], 65536 each
#define OFF_W1  393216   // OUT=512 K=256
#define OFF_W2  524288   // OUT=256 K=512
#define OFF_WV  655360   // OUT=256 K=256
#define OFF_WQ  720896   // OUT=256 K=256
#define OFF_WK  786432   // OUT=256(j) K=256(d), src Wk[d*256+j]
#define WB_ELEMS 851968

#define G_PRE (BB * KK)              // 256
#define G_W2B (512 * 11)             // 5632
#define G_SETUP (G_PRE + G_W2B)

__device__ __forceinline__ float dotp4(uint2 w, float4 s) {
  return __uint_as_float(w.x << 16) * s.x + __uint_as_float(w.x & 0xffff0000u) * s.y +
         __uint_as_float(w.y << 16) * s.z + __uint_as_float(w.y & 0xffff0000u) * s.w;
}

// coalesced packed GEMV partial: output j, k in [kb, kb+KL)
template <int OUT, int KL>
__device__ __forceinline__ float gemv_p(const ushort* __restrict__ wt, int j, int kb,
                                        const float* __restrict__ src) {
  const uint2* p = (const uint2*)(wt + ((size_t)(kb >> 2) * OUT + j) * 4);
  float a = 0.0f;
#pragma unroll 16
  for (int e = 0; e < KL / 4; ++e) {
    uint2 w = p[(size_t)e * OUT];
    float4 s = *(const float4*)(src + kb + e * 4);
    a += dotp4(w, s);
  }
  return a;
}

// ---------- Kernel 1 (setup): slots_pre (blocks [0,256)) + w2b (rest) ----------
__global__ __launch_bounds__(256) void k_setup(
    const float* __restrict__ Wih, const float* __restrict__ Whh,
    const float* __restrict__ W1, const float* __restrict__ W2,
    const float* __restrict__ Wv, const float* __restrict__ Wq,
    const float* __restrict__ Wk, ushort* __restrict__ wb,
    const float* __restrict__ slots, const float* __restrict__ gs, const float* __restrict__ bs,
    const float* __restrict__ bq, const float* __restrict__ bk,
    float* __restrict__ qk, float* __restrict__ qb) {
  int blk = blockIdx.x;
  if (blk < G_PRE) {
    // ---- initial qk/qb from slots_init (fp32 weights) ----
    int row = blk;
    int t = threadIdx.x;
    int wid = t >> 6, lane = t & 63;
    __shared__ float lns[DD];
    __shared__ float qs[DD];
    __shared__ float rb[8];
    float sv = slots[(size_t)row * DD + t];
    float s = wave_sum(sv);
    float s2 = wave_sum(sv * sv);
    if (lane == 0) { rb[wid] = s; rb[4 + wid] = s2; }
    __syncthreads();
    float tot = rb[0] + rb[1] + rb[2] + rb[3];
    float tot2 = rb[4] + rb[5] + rb[6] + rb[7];
    float m = tot * (1.0f / DD);
    float var = tot2 * (1.0f / DD) - m * m;
    float rs = rsqrtf(var + LN_EPS);
    lns[t] = (sv - m) * rs * gs[t] + bs[t];
    __syncthreads();
    float acc = 0.0f;
    const float4* wr = (const float4*)(Wq + (size_t)t * DD);
#pragma unroll 4
    for (int e4 = 0; e4 < DD / 4; ++e4) {
      float4 w = wr[e4];
      float4 l = ((const float4*)lns)[e4];
      acc += w.x * l.x + w.y * l.y + w.z * l.z + w.w * l.w;
    }
    qs[t] = acc + bq[t];
    __syncthreads();
    float a2 = 0.0f;
    for (int d = 0; d < DD; ++d) a2 = fmaf(qs[d], Wk[(size_t)d * DD + t], a2);
    qk[(size_t)row * DD + t] = SCALE * a2;
    float pb = wave_sum(qs[t] * bk[t]);
    __syncthreads();
    if (lane == 0) rb[wid] = pb;
    __syncthreads();
    if (t == 0) qb[row] = SCALE * (rb[0] + rb[1] + rb[2] + rb[3]);
  } else {
    // ---- pack weights to bf16 ----
    int q2 = blk - G_PRE;
    int m = q2 >> 9;             // /512
    int idx = (q2 & 511) * 256 + threadIdx.x;
    const int sizes[11] = {65536, 65536, 65536, 65536, 65536, 65536, 131072, 131072, 65536, 65536, 65536};
    const int offs[11] = {OFF_G, OFF_G + 65536, OFF_G + 131072, OFF_G + 196608, OFF_G + 262144,
                          OFF_G + 327680, OFF_W1, OFF_W2, OFF_WV, OFF_WQ, OFF_WK};
    if (idx >= sizes[m]) return;
    int K = (m == 7) ? 512 : 256;
    int OUT = (m == 6) ? 512 : 256;
    int k = idx % K, j = idx / K;
    float v;
    switch (m) {
      case 0: case 1: case 2: v = Wih[((size_t)(m * 256 + j)) * 256 + k]; break;
      case 3: case 4: case 5: v = Whh[((size_t)((m - 3) * 256 + j)) * 256 + k]; break;
      case 6: v = W1[(size_t)j * 256 + k]; break;
      case 7: v = W2[(size_t)j * 512 + k]; break;
      case 8: v = Wv[(size_t)j * 256 + k]; break;
      case 9: v = Wq[(size_t)j * 256 + k]; break;
      default: v = Wk[(size_t)k * 256 + j]; break;
    }
    __hip_bfloat16 h = __float2bfloat16(v);
    wb[(size_t)offs[m] + (size_t)(k >> 2) * OUT * 4 + j * 4 + (k & 3)] = *(ushort*)&h;
  }
}

// ---------- Kernel 3: streaming attention, multi-value fold reduce ----------
// DO_LN=1: iteration 0 — reads fp32 inputs, does LayerNorm in-register, writes bf16 xb.
// DO_LN=0: iterations 1,2 — reads bf16 xb.
// Lane-permuted softmax: after fold, lane holds logit for k=km(lane&7);
// km(l) = ((l&1)<<2) | (l&2) | ((l>>2)&1).
// Grid: BB * NCHUNK blocks; each wave handles 32 rows (16 iterations x 2 rows).
template <int DO_LN>
__global__ __launch_bounds__(256) void k_attn_t(const ushort* __restrict__ xb_in,
                                                ushort* __restrict__ xb_out,
                                                const float* __restrict__ inp,
                                                const float* __restrict__ lg,
                                                const float* __restrict__ lb,
                                                const float* __restrict__ qk,
                                                const float* __restrict__ qb,
                                                float* __restrict__ uxp,
                                                float* __restrict__ sap) {
  int wid = threadIdx.x >> 6, lane = threadIdx.x & 63;
  int wg = blockIdx.x * 4 + wid;
  int b = wg >> 7, wc = wg & 127;
  int l32 = lane & 31, half = lane >> 5;
  int d0 = l32 * 8;
  __shared__ float bx[KK][DD];
  __shared__ float sred[4][KK];
  float4 qa[8], qc[8];
  {
    const float* base = qk + (size_t)b * (KK * DD) + d0;
#pragma unroll
    for (int k = 0; k < 8; ++k) {
      qa[k] = *(const float4*)(base + k * DD);
      qc[k] = *(const float4*)(base + k * DD + 4);
    }
  }
  int km = ((lane & 1) << 2) | (lane & 2) | ((lane >> 2) & 1);
  float qb_mine = qb[b * 8 + km];
  float g8[8], b8[8];
  const float* rp;
  ushort* wp;
  const uint4* px;
  uint4 xv;
  if (DO_LN) {
#pragma unroll
    for (int j = 0; j < 8; ++j) { g8[j] = lg[d0 + j]; b8[j] = lb[d0 + j]; }
    rp = inp + ((size_t)b * NN + wc * 32 + half) * DD + d0;
    wp = xb_out + ((size_t)b * NN + wc * 32 + half) * DD + d0;
  } else {
    px = (const uint4*)(xb_in + ((size_t)b * NN + wc * 32 + half) * DD + d0);
    xv = px[0];
  }
  float4 ac0[8] = {}, ac1[8] = {};
  float sacc = 0.0f;
#pragma unroll 2
  for (int it = 0; it < 16; ++it) {
    float xf[8];
    if (DO_LN) {
      float4 v0 = *(const float4*)rp;
      float4 v1 = *(const float4*)(rp + 4);
      float s = v0.x + v0.y + v0.z + v0.w + v1.x + v1.y + v1.z + v1.w;
      float s2 = v0.x * v0.x + v0.y * v0.y + v0.z * v0.z + v0.w * v0.w +
                 v1.x * v1.x + v1.y * v1.y + v1.z * v1.z + v1.w * v1.w;
#pragma unroll
      for (int off = 16; off >= 1; off >>= 1) {
        s += __shfl_xor(s, off);
        s2 += __shfl_xor(s2, off);
      }
      float m = s * (1.0f / DD);
      float var = s2 * (1.0f / DD) - m * m;
      float rs = rsqrtf(var + LN_EPS);
      xf[0] = (v0.x - m) * rs * g8[0] + b8[0];
      xf[1] = (v0.y - m) * rs * g8[1] + b8[1];
      xf[2] = (v0.z - m) * rs * g8[2] + b8[2];
      xf[3] = (v0.w - m) * rs * g8[3] + b8[3];
      xf[4] = (v1.x - m) * rs * g8[4] + b8[4];
      xf[5] = (v1.y - m) * rs * g8[5] + b8[5];
      xf[6] = (v1.z - m) * rs * g8[6] + b8[6];
      xf[7] = (v1.w - m) * rs * g8[7] + b8[7];
      uint4 st;
      {
        __hip_bfloat16 h0 = __float2bfloat16(xf[0]), h1 = __float2bfloat16(xf[1]);
        __hip_bfloat16 h2 = __float2bfloat16(xf[2]), h3 = __float2bfloat16(xf[3]);
        __hip_bfloat16 h4 = __float2bfloat16(xf[4]), h5 = __float2bfloat16(xf[5]);
        __hip_bfloat16 h6 = __float2bfloat16(xf[6]), h7 = __float2bfloat16(xf[7]);
        st.x = (uint)*(ushort*)&h0 | ((uint)*(ushort*)&h1 << 16);
        st.y = (uint)*(ushort*)&h2 | ((uint)*(ushort*)&h3 << 16);
        st.z = (uint)*(ushort*)&h4 | ((uint)*(ushort*)&h5 << 16);
        st.w = (uint)*(ushort*)&h6 | ((uint)*(ushort*)&h7 << 16);
      }
      *(uint4*)wp = st;
      rp += 2 * DD;
      wp += 2 * DD;
    } else {
      uint4 nx = (it < 15) ? px[(size_t)(it + 1) * 64] : xv;
      xf[0] = __uint_as_float(xv.x << 16); xf[1] = __uint_as_float(xv.x & 0xffff0000u);
      xf[2] = __uint_as_float(xv.y << 16); xf[3] = __uint_as_float(xv.y & 0xffff0000u);
      xf[4] = __uint_as_float(xv.z << 16); xf[5] = __uint_as_float(xv.z & 0xffff0000u);
      xf[6] = __uint_as_float(xv.w << 16); xf[7] = __uint_as_float(xv.w & 0xffff0000u);
      xv = nx;
    }
    float l[8];
#pragma unroll
    for (int k = 0; k < 8; ++k) {
      l[k] = xf[0] * qa[k].x + xf[1] * qa[k].y + xf[2] * qa[k].z + xf[3] * qa[k].w +
             xf[4] * qc[k].x + xf[5] * qc[k].y + xf[6] * qc[k].z + xf[7] * qc[k].w;
    }
    // fold 8 values -> 1 per lane (k = km(lane&7)), reducing lanes xor 1,2,4
#pragma unroll
    for (int i = 0; i < 4; ++i) {
      float keep = (lane & 1) ? l[i + 4] : l[i];
      float send = (lane & 1) ? l[i] : l[i + 4];
      l[i] = keep + __shfl_xor(send, 1);
    }
#pragma unroll
    for (int i = 0; i < 2; ++i) {
      float keep = (lane & 2) ? l[i + 2] : l[i];
      float send = (lane & 2) ? l[i] : l[i + 2];
      l[i] = keep + __shfl_xor(send, 2);
    }
    {
      float keep = (lane & 4) ? l[1] : l[0];
      float send = (lane & 4) ? l[0] : l[1];
      l[0] = keep + __shfl_xor(send, 4);
    }
    float lv = l[0] + __shfl_xor(l[0], 8);
    lv += __shfl_xor(lv, 16);
    lv += qb_mine;
    // softmax over k == over lane bits 0-2
    float mx = fmaxf(lv, __shfl_xor(lv, 1));
    mx = fmaxf(mx, __shfl_xor(mx, 2));
    mx = fmaxf(mx, __shfl_xor(mx, 4));
    float p = __expf(lv - mx);
    float ss = p + __shfl_xor(p, 1);
    ss += __shfl_xor(ss, 2);
    ss += __shfl_xor(ss, 4);
    float a = p * __frcp_rn(ss);
    sacc += a;
    // gather: ga[j] = a-value of lane^j  (k = km((lane^j)&7))
    float ga[8];
    ga[0] = a;
    ga[1] = __shfl_xor(ga[0], 1);
    ga[2] = __shfl_xor(ga[0], 2);
    ga[3] = __shfl_xor(ga[1], 2);
    ga[4] = __shfl_xor(ga[0], 4);
    ga[5] = __shfl_xor(ga[1], 4);
    ga[6] = __shfl_xor(ga[2], 4);
    ga[7] = __shfl_xor(ga[3], 4);
#pragma unroll
    for (int j = 0; j < 8; ++j) {
      float aj = ga[j];
      ac0[j].x = fmaf(aj, xf[0], ac0[j].x);
      ac0[j].y = fmaf(aj, xf[1], ac0[j].y);
      ac0[j].z = fmaf(aj, xf[2], ac0[j].z);
      ac0[j].w = fmaf(aj, xf[3], ac0[j].w);
      ac1[j].x = fmaf(aj, xf[4], ac1[j].x);
      ac1[j].y = fmaf(aj, xf[5], ac1[j].y);
      ac1[j].z = fmaf(aj, xf[6], ac1[j].z);
      ac1[j].w = fmaf(aj, xf[7], ac1[j].w);
    }
  }
  // combine halves (lane and lane^32 share the same k-permutation)
#pragma unroll
  for (int j = 0; j < 8; ++j) {
    ac0[j].x += __shfl_xor(ac0[j].x, 32);
    ac0[j].y += __shfl_xor(ac0[j].y, 32);
    ac0[j].z += __shfl_xor(ac0[j].z, 32);
    ac0[j].w += __shfl_xor(ac0[j].w, 32);
    ac1[j].x += __shfl_xor(ac1[j].x, 32);
    ac1[j].y += __shfl_xor(ac1[j].y, 32);
    ac1[j].z += __shfl_xor(ac1[j].z, 32);
    ac1[j].w += __shfl_xor(ac1[j].w, 32);
  }
  sacc += __shfl_xor(sacc, 32);
  if (lane < 8) sred[wid][km] = sacc;
  // staged block combine into bx with k un-permutation
#pragma unroll
  for (int w = 0; w < 4; ++w) {
    if (wid == w && half == 0) {
#pragma unroll
      for (int j = 0; j < 8; ++j) {
        int lx = (l32 ^ j) & 7;
        int kj = ((lx & 1) << 2) | (lx & 2) | ((lx >> 2) & 1);
        float4* p0 = (float4*)&bx[kj][d0];
        float4* p1 = (float4*)&bx[kj][d0 + 4];
        if (w == 0) {
          *p0 = ac0[j];
          *p1 = ac1[j];
        } else {
          float4 c0 = *p0, c1 = *p1;
          c0.x += ac0[j].x; c0.y += ac0[j].y; c0.z += ac0[j].z; c0.w += ac0[j].w;
          c1.x += ac1[j].x; c1.y += ac1[j].y; c1.z += ac1[j].z; c1.w += ac1[j].w;
          *p0 = c0; *p1 = c1;
        }
      }
    }
    __syncthreads();
  }
  int bb2 = blockIdx.x >> 5, c = blockIdx.x & 31;
  {
    int t = threadIdx.x;
    int k = t >> 5, dd = (t & 31) * 8;
    float* dst = uxp + (((size_t)(bb2 * NCHUNK + c)) * KK + k) * DD + dd;
    *(float4*)dst = *(float4*)&bx[k][dd];
    *(float4*)(dst + 4) = *(float4*)&bx[k][dd + 4];
    if (t < 8)
      sap[((size_t)(bb2 * NCHUNK + c)) * KK + t] =
          sred[0][t] + sred[1][t] + sred[2][t] + sred[3][t];
  }
}

// ---------- Kernel 4: fused slot update, 1 row (b,k) per block, 1024 threads ----------
__global__ __launch_bounds__(1024) void k_fused(const float* __restrict__ slots_in,
                                                const float* __restrict__ uxp,
                                                const float* __restrict__ sap,
                                                const ushort* __restrict__ wb,
                                                const float* __restrict__ bv,
                                                const float* __restrict__ bih, const float* __restrict__ bhh,
                                                const float* __restrict__ gff, const float* __restrict__ bff,
                                                const float* __restrict__ b1, const float* __restrict__ b2,
                                                const float* __restrict__ gs, const float* __restrict__ bs,
                                                const float* __restrict__ bq, const float* __restrict__ bk,
                                                float* __restrict__ dst,
                                                float* __restrict__ qk_out,
                                                float* __restrict__ qb_out,
                                                int last) {
  const ushort* WG = wb + OFF_G;
  const ushort* W1p = wb + OFF_W1;
  const ushort* W2p = wb + OFF_W2;
  const ushort* WVp = wb + OFF_WV;
  const ushort* WQp = wb + OFF_WQ;
  const ushort* WKp = wb + OFF_WK;

  __shared__ float ux_s[DD], h_s[DD], upd_s[DD], hn_s[DD], ln_s[DD];
  __shared__ float g_s[6][DD];
  __shared__ float hdd_s[HH];
  __shared__ float tmp4_s[4][DD];
  __shared__ float red_s[16];
  __shared__ float sA_s;
  float* tmpH = &tmp4_s[0][0];  // [2][512] alias

  int t = threadIdx.x, d = t & 255, qr = t >> 8;
  int wid = t >> 6, lane = t & 63;
  int r = blockIdx.x, b = r >> 3, k = r & 7;

  // ---- phase 0: reduce 32 attention partials; load h; reduce sA ----
  {
    const float* p = uxp + (((size_t)(b * NCHUNK + qr * 8)) * KK + k) * DD + d;
    float s = 0.0f;
#pragma unroll
    for (int i = 0; i < 8; ++i) s += p[(size_t)i * KK * DD];
    tmp4_s[qr][d] = s;
  }
  if (t < 256) h_s[t] = slots_in[(size_t)r * DD + t];
  if (t >= 960) {
    int c = t - 960;
    float v = (c < NCHUNK) ? sap[((size_t)(b * NCHUNK + c)) * KK + k] : 0.0f;
    v = wave_sum(v);
    if (lane == 0) sA_s = v;
  }
  __syncthreads();
  if (t < 256) ux_s[t] = tmp4_s[0][t] + tmp4_s[1][t] + tmp4_s[2][t] + tmp4_s[3][t];
  __syncthreads();

  // ---- phase 1: upd = Wv.ux + bv*sA (K-split-4, coalesced) ----
  tmp4_s[qr][d] = gemv_p<256, 64>(WVp, d, qr * 64, ux_s);
  __syncthreads();
  if (t < 256) upd_s[t] = tmp4_s[0][t] + tmp4_s[1][t] + tmp4_s[2][t] + tmp4_s[3][t] + bv[t] * sA_s;
  __syncthreads();

  // ---- phase 2: GRU gates — 1536 full-K coalesced dots in 1.5 rounds ----
  {
    int g = qr;  // 0..3: ih_r, ih_z, ih_n, hh_r
    const float* src = (g < 3) ? upd_s : h_s;
    float a = gemv_p<256, 256>(WG + (size_t)g * 65536, d, 0, src);
    g_s[g][d] = a + ((g < 3) ? bih[g * 256 + d] : bhh[d]);
    if (t < 512) {
      int g2 = 4 + (t >> 8), j2 = t & 255;  // hh_z, hh_n
      float a2 = gemv_p<256, 256>(WG + (size_t)g2 * 65536, j2, 0, h_s);
      g_s[g2][j2] = a2 + bhh[(g2 - 3) * 256 + j2];
    }
  }
  __syncthreads();
  if (t < 256) {
    float rr = sigmoidf_(g_s[0][t] + g_s[3][t]);
    float zz = sigmoidf_(g_s[1][t] + g_s[4][t]);
    float nn = tanhf(g_s[2][t] + rr * g_s[5][t]);
    hn_s[t] = (1.0f - zz) * nn + zz * h_s[t];
  }
  __syncthreads();

  // ---- phase 3: LN(hn) with ff params ----
  if (t < 256) {
    float v = hn_s[t];
    float sm = wave_sum(v), sq = wave_sum(v * v);
    if (lane == 0) { red_s[wid] = sm; red_s[8 + wid] = sq; }
  }
  __syncthreads();
  if (t < 256) {
    float v = hn_s[t];
    float tot = red_s[0] + red_s[1] + red_s[2] + red_s[3];
    float tot2 = red_s[8] + red_s[9] + red_s[10] + red_s[11];
    float m = tot * (1.0f / DD);
    float var = tot2 * (1.0f / DD) - m * m;
    float rs = rsqrtf(var + LN_EPS);
    ln_s[t] = (v - m) * rs * gff[t] + bff[t];
  }
  __syncthreads();

  // ---- phase 4: hdd = relu(W1.ln + b1) (512 outs, K-split-2, coalesced) ----
  {
    int o = t & 511, kh = t >> 9;
    tmpH[kh * 512 + o] = gemv_p<512, 128>(W1p, o, kh * 128, ln_s);
  }
  __syncthreads();
  if (t < 512) hdd_s[t] = fmaxf(tmpH[t] + tmpH[512 + t] + b1[t], 0.0f);
  __syncthreads();

  // ---- phase 5: out = hn + W2.hdd + b2 (K=512, K-split-4, coalesced) ----
  tmp4_s[qr][d] = gemv_p<256, 128>(W2p, d, qr * 128, hdd_s);
  __syncthreads();
  if (t < 256) {
    float o = hn_s[t] + tmp4_s[0][t] + tmp4_s[1][t] + tmp4_s[2][t] + tmp4_s[3][t] + b2[t];
    dst[(size_t)r * DD + t] = o;
    ux_s[t] = o;  // new slots
  }
  __syncthreads();

  if (!last) {
    // ---- 6a: LN(new slots) with slot params ----
    if (t < 256) {
      float v = ux_s[t];
      float sm = wave_sum(v), sq = wave_sum(v * v);
      if (lane == 0) { red_s[wid] = sm; red_s[8 + wid] = sq; }
    }
    __syncthreads();
    if (t < 256) {
      float v = ux_s[t];
      float tot = red_s[0] + red_s[1] + red_s[2] + red_s[3];
      float tot2 = red_s[8] + red_s[9] + red_s[10] + red_s[11];
      float m = tot * (1.0f / DD);
      float var = tot2 * (1.0f / DD) - m * m;
      float rs = rsqrtf(var + LN_EPS);
      ln_s[t] = (v - m) * rs * gs[t] + bs[t];
    }
    __syncthreads();
    // ---- 6b: q = Wq.ln + bq (K-split-4, coalesced) ----
    tmp4_s[qr][d] = gemv_p<256, 64>(WQp, d, qr * 64, ln_s);
    __syncthreads();
    if (t < 256) {
      float qv = tmp4_s[0][t] + tmp4_s[1][t] + tmp4_s[2][t] + tmp4_s[3][t] + bq[t];
      upd_s[t] = qv;  // q row
      float sb = wave_sum(qv * bk[t]);
      if (lane == 0) red_s[wid] = sb;
    }
    __syncthreads();
    // ---- 6c: qk[j] = SCALE * dot over d (K-split-4, coalesced) ----
    {
      float a = gemv_p<256, 64>(WKp, d, qr * 64, upd_s);
      tmp4_s[qr][d] = a;
    }
    __syncthreads();
    if (t < 256) qk_out[(size_t)r * DD + t] =
        SCALE * (tmp4_s[0][t] + tmp4_s[1][t] + tmp4_s[2][t] + tmp4_s[3][t]);
    if (t == 0) qb_out[r] = SCALE * (red_s[0] + red_s[1] + red_s[2] + red_s[3]);
  }
}

extern "C" void kernel_launch(void* const* d_in, const int* in_sizes, int n_in,
                              void* d_out, int out_size, void* d_ws, size_t ws_size,
                              hipStream_t stream) {
  const float* inputs = (const float*)d_in[0];
  const float* slots_init = (const float*)d_in[1];
  const float* ln_in_g = (const float*)d_in[2];
  const float* ln_in_b = (const float*)d_in[3];
  const float* ln_s_g = (const float*)d_in[4];
  const float* ln_s_b = (const float*)d_in[5];
  const float* ln_ff_g = (const float*)d_in[6];
  const float* ln_ff_b = (const float*)d_in[7];
  const float* Wk = (const float*)d_in[8];
  const float* bk = (const float*)d_in[9];
  const float* Wq = (const float*)d_in[10];
  const float* bq = (const float*)d_in[11];
  const float* Wv = (const float*)d_in[12];
  const float* bv = (const float*)d_in[13];
  const float* Wih = (const float*)d_in[14];
  const float* bih = (const float*)d_in[15];
  const float* Whh = (const float*)d_in[16];
  const float* bhh = (const float*)d_in[17];
  const float* W1 = (const float*)d_in[18];
  const float* b1 = (const float*)d_in[19];
  const float* W2 = (const float*)d_in[20];
  const float* b2 = (const float*)d_in[21];
  float* outp = (float*)d_out;

  char* w = (char*)d_ws;
  ushort* xb = (ushort*)w;       w += (size_t)BB * NN * DD * 2;
  float* qk = (float*)w;         w += (size_t)BB * KK * DD * 4;
  float* qb = (float*)w;         w += (size_t)BB * KK * 4;
  float* uxp = (float*)w;        w += (size_t)BB * NCHUNK * KK * DD * 4;
  float* sap = (float*)w;        w += (size_t)BB * NCHUNK * KK * 4;
  float* slots_ws = (float*)w;   w += (size_t)BB * KK * DD * 4;
  ushort* wb = (ushort*)w;       w += (size_t)WB_ELEMS * 2;

  k_setup<<<G_SETUP, 256, 0, stream>>>(Wih, Whh, W1, W2, Wv, Wq, Wk, wb,
                                       slots_init, ln_s_g, ln_s_b, bq, bk, qk, qb);

  for (int it = 0; it < 3; ++it) {
    if (it == 0)
      k_attn_t<1><<<BB * NCHUNK, 256, 0, stream>>>(nullptr, xb, inputs, ln_in_g, ln_in_b,
                                                   qk, qb, uxp, sap);
    else
      k_attn_t<0><<<BB * NCHUNK, 256, 0, stream>>>(xb, nullptr, nullptr, nullptr, nullptr,
                                                   qk, qb, uxp, sap);
    const float* sin = (it == 0) ? slots_init : slots_ws;
    float* dst = (it == 2) ? outp : slots_ws;
    k_fused<<<BB * KK, 1024, 0, stream>>>(sin, uxp, sap, wb,
                                          bv, bih, bhh, ln_ff_g, ln_ff_b, b1, b2,
                                          ln_s_g, ln_s_b, bq, bk,
                                          dst, qk, qb, (it == 2) ? 1 : 0);
  }
}